// Round 1
// baseline (2354.972 us; speedup 1.0000x reference)
//
#include <hip/hip_runtime.h>
#include <math.h>

// Problem constants (B=32, S=2048, D=256, K=2048)
constexpr int R_TOT = 32 * 2048;   // 65536 rows
constexpr int D     = 256;         // half-dim
constexpr int D2    = 512;         // full dim (real||imag)
constexpr int K     = 2048;        // codebook size

constexpr int BM = 64;             // rows per block
constexpr int BN = 64;             // codewords per N-tile
constexpr int BD = 32;             // D-chunk staged in LDS
constexpr int NTHREADS = 256;

constexpr float LOSS_SCALE = 1.25f / ((float)R_TOT * (float)D2);

// ---------------------------------------------------------------------------
// cnorm[k] = ||codebook[k]||^2   (K rows of 512) — one wave per row
__global__ __launch_bounds__(256)
void k_cnorm(const float* __restrict__ cb, float* __restrict__ cnorm) {
    int row  = (blockIdx.x << 2) + (threadIdx.x >> 6);
    int lane = threadIdx.x & 63;
    const float4* p = reinterpret_cast<const float4*>(cb + (size_t)row * D2 + lane * 8);
    float4 a = p[0], b = p[1];
    float s = a.x*a.x + a.y*a.y + a.z*a.z + a.w*a.w
            + b.x*b.x + b.y*b.y + b.z*b.z + b.w*b.w;
    #pragma unroll
    for (int o = 32; o > 0; o >>= 1) s += __shfl_down(s, o, 64);
    if (lane == 0) cnorm[row] = s;
}

// ---------------------------------------------------------------------------
// Main fused kernel: tiled fp32 GEMM (z . c^T) + sigmoid graph bias + argmin
// + z_q gather-out + loss reduction.
__global__ __launch_bounds__(NTHREADS)
void k_vq(const float* __restrict__ zr, const float* __restrict__ zi,
          const int*   __restrict__ prev, const float* __restrict__ cb,
          const float* __restrict__ adj,  const float* __restrict__ cnorm,
          float* __restrict__ out_real, float* __restrict__ out_imag,
          float* __restrict__ loss, float* __restrict__ out_idx) {
    // padded to stride 68 dwords: keeps float4 alignment (68%4==0) and rotates banks
    __shared__ float zs[BD][BM + 4];
    __shared__ float cs[BD][BN + 4];
    __shared__ float s_minv[BM][17];
    __shared__ int   s_mini[BM][17];
    __shared__ int   s_kmin[BM];

    const int tid  = threadIdx.x;
    const int tx   = tid & 15;        // 16 column-groups
    const int ty   = tid >> 4;        // 16 row-groups
    const int row0 = blockIdx.x * BM;

    int pidx[4];
    #pragma unroll
    for (int i = 0; i < 4; ++i) pidx[i] = prev[row0 + ty * 4 + i];

    float minv[4]; int mini[4];
    #pragma unroll
    for (int i = 0; i < 4; ++i) { minv[i] = 3.0e38f; mini[i] = 0; }

    for (int nt = 0; nt < K / BN; ++nt) {
        float acc[4][4];
        #pragma unroll
        for (int i = 0; i < 4; ++i)
            #pragma unroll
            for (int j = 0; j < 4; ++j) acc[i][j] = 0.0f;

        for (int dk = 0; dk < D2; dk += BD) {
            __syncthreads();
            // ---- stage z tile (transposed: zs[d][row]) ----
            const float* zsrc = (dk < D) ? (zr + (size_t)row0 * D + dk)
                                         : (zi + (size_t)row0 * D + (dk - D));
            #pragma unroll
            for (int s = 0; s < 2; ++s) {
                int slot = tid + s * 256;           // 512 float4 slots
                int r = slot >> 3, d4 = slot & 7;   // 64 rows x 8 float4
                float4 v = *reinterpret_cast<const float4*>(zsrc + r * D + d4 * 4);
                zs[d4*4+0][r] = v.x; zs[d4*4+1][r] = v.y;
                zs[d4*4+2][r] = v.z; zs[d4*4+3][r] = v.w;
            }
            // ---- stage codebook tile (transposed: cs[d][col]) ----
            const float* csrc = cb + (size_t)(nt * BN) * D2 + dk;
            #pragma unroll
            for (int s = 0; s < 2; ++s) {
                int slot = tid + s * 256;
                int r = slot >> 3, d4 = slot & 7;
                float4 v = *reinterpret_cast<const float4*>(csrc + r * D2 + d4 * 4);
                cs[d4*4+0][r] = v.x; cs[d4*4+1][r] = v.y;
                cs[d4*4+2][r] = v.z; cs[d4*4+3][r] = v.w;
            }
            __syncthreads();
            // ---- 4x4 microtile FMA over the chunk ----
            #pragma unroll
            for (int d = 0; d < BD; ++d) {
                float4 av = *reinterpret_cast<const float4*>(&zs[d][ty * 4]);
                float4 bv = *reinterpret_cast<const float4*>(&cs[d][tx * 4]);
                float a_[4] = {av.x, av.y, av.z, av.w};
                float b_[4] = {bv.x, bv.y, bv.z, bv.w};
                #pragma unroll
                for (int i = 0; i < 4; ++i)
                    #pragma unroll
                    for (int j = 0; j < 4; ++j)
                        acc[i][j] += a_[i] * b_[j];
            }
        }

        // ---- score + running argmin for this N-tile ----
        const int kbase = nt * BN + tx * 4;
        float4 cn4 = *reinterpret_cast<const float4*>(cnorm + kbase);
        float cn_[4] = {cn4.x, cn4.y, cn4.z, cn4.w};
        #pragma unroll
        for (int i = 0; i < 4; ++i) {
            float4 g4 = *reinterpret_cast<const float4*>(adj + (size_t)pidx[i] * K + kbase);
            float g_[4] = {g4.x, g4.y, g4.z, g4.w};
            #pragma unroll
            for (int j = 0; j < 4; ++j) {
                float sc = cn_[j] - 2.0f * acc[i][j]
                         - 0.5f / (1.0f + __expf(-g_[j]));
                int k = kbase + j;
                if (sc < minv[i]) { minv[i] = sc; mini[i] = k; }
            }
        }
    }

    // ---- cross-thread argmin reduction (16 col-groups per row) ----
    #pragma unroll
    for (int i = 0; i < 4; ++i) {
        s_minv[ty * 4 + i][tx] = minv[i];
        s_mini[ty * 4 + i][tx] = mini[i];
    }
    __syncthreads();
    if (tid < BM) {
        float bv = s_minv[tid][0]; int bi = s_mini[tid][0];
        #pragma unroll
        for (int t = 1; t < 16; ++t) {
            float v = s_minv[tid][t]; int idx = s_mini[tid][t];
            if (v < bv || (v == bv && idx < bi)) { bv = v; bi = idx; }
        }
        s_kmin[tid] = bi;
        out_idx[row0 + tid] = (float)bi;
    }
    __syncthreads();

    // ---- epilogue: z_q gather -> out, loss partials ----
    float lsum = 0.0f;
    for (int r = 0; r < BM; ++r) {
        int k  = s_kmin[r];
        int gr = row0 + r;
        float2 c2 = *reinterpret_cast<const float2*>(cb + (size_t)k * D2 + tid * 2);
        float2 z2;
        float* outp;
        if (tid < 128) {
            z2   = *reinterpret_cast<const float2*>(zr + (size_t)gr * D + tid * 2);
            outp = out_real + (size_t)gr * D + tid * 2;
        } else {
            z2   = *reinterpret_cast<const float2*>(zi + (size_t)gr * D + (tid - 128) * 2);
            outp = out_imag + (size_t)gr * D + (tid - 128) * 2;
        }
        *reinterpret_cast<float2*>(outp) = c2;
        float d0 = c2.x - z2.x, d1 = c2.y - z2.y;
        lsum += d0 * d0 + d1 * d1;
    }

    // block-reduce loss, one atomic per block
    #pragma unroll
    for (int o = 32; o > 0; o >>= 1) lsum += __shfl_down(lsum, o, 64);
    __shared__ float s_ls[4];
    int wid = tid >> 6, lane = tid & 63;
    if (lane == 0) s_ls[wid] = lsum;
    __syncthreads();
    if (tid == 0) {
        float tot = s_ls[0] + s_ls[1] + s_ls[2] + s_ls[3];
        atomicAdd(loss, tot * LOSS_SCALE);
    }
}

// ---------------------------------------------------------------------------
extern "C" void kernel_launch(void* const* d_in, const int* in_sizes, int n_in,
                              void* d_out, int out_size, void* d_ws, size_t ws_size,
                              hipStream_t stream) {
    const float* zr   = (const float*)d_in[0];
    const float* zi   = (const float*)d_in[1];
    const int*   prev = (const int*)  d_in[2];
    const float* cb   = (const float*)d_in[3];
    const float* adj  = (const float*)d_in[4];

    float* out      = (float*)d_out;
    float* out_real = out;
    float* out_imag = out + (size_t)R_TOT * D;
    float* loss     = out + (size_t)2 * R_TOT * D;   // single element
    float* out_idx  = loss + 1;                      // R_TOT elements (as float)

    float* cnorm = (float*)d_ws;                     // K floats of scratch

    hipMemsetAsync(loss, 0, sizeof(float), stream);
    k_cnorm<<<K / 4, 256, 0, stream>>>(cb, cnorm);
    k_vq<<<R_TOT / BM, NTHREADS, 0, stream>>>(zr, zi, prev, cb, adj, cnorm,
                                              out_real, out_imag, loss, out_idx);
}

// Round 2
// 1262.387 us; speedup vs baseline: 1.8655x; 1.8655x over previous
//
#include <hip/hip_runtime.h>
#include <math.h>

typedef _Float16 half8 __attribute__((ext_vector_type(8)));
typedef _Float16 half4v __attribute__((ext_vector_type(4)));
typedef float floatx4 __attribute__((ext_vector_type(4)));

constexpr int R_TOT = 65536;   // B*S
constexpr int D     = 256;
constexpr int D2    = 512;
constexpr int K     = 2048;
constexpr float LOSS_SCALE = 1.25f / ((float)R_TOT * (float)D2);

// async global->LDS, 16B per lane; LDS dest = wave-uniform base + lane*16
__device__ __forceinline__ void async16(void* lds, const void* g) {
    __builtin_amdgcn_global_load_lds(
        (const __attribute__((address_space(1))) unsigned int*)g,
        (__attribute__((address_space(3))) unsigned int*)lds,
        16, 0, 0);
}

// ---------------------------------------------------------------------------
// Split one fp32 [R][256] source into hi/lo fp16 halves of [R][512] dest.
__global__ __launch_bounds__(256)
void k_split(const float* __restrict__ src, _Float16* __restrict__ dhi,
             _Float16* __restrict__ dlo, int coloff) {
    const int n4 = R_TOT * 64;                       // float4 count
    for (int i = blockIdx.x * blockDim.x + threadIdx.x; i < n4;
         i += gridDim.x * blockDim.x) {
        int row = i >> 6, c4 = i & 63;
        float4 v = reinterpret_cast<const float4*>(src)[i];
        float vv[4] = {v.x, v.y, v.z, v.w};
        half4v h, l;
        #pragma unroll
        for (int j = 0; j < 4; ++j) {
            _Float16 hj = (_Float16)vv[j];
            h[j] = hj;
            l[j] = (_Float16)(vv[j] - (float)hj);
        }
        size_t di = (size_t)row * D2 + coloff + c4 * 4;
        *reinterpret_cast<half4v*>(dhi + di) = h;
        *reinterpret_cast<half4v*>(dlo + di) = l;
    }
}

// ---------------------------------------------------------------------------
// Split codebook [K][512] into hi/lo fp16 + exact fp32 row norms. Wave/row.
__global__ __launch_bounds__(256)
void k_split_cb(const float* __restrict__ cb, _Float16* __restrict__ chi,
                _Float16* __restrict__ clo, float* __restrict__ cnorm) {
    int row  = blockIdx.x * 4 + (threadIdx.x >> 6);
    int lane = threadIdx.x & 63;
    const float4* p = reinterpret_cast<const float4*>(cb + (size_t)row * D2 + lane * 8);
    float s = 0.0f;
    #pragma unroll
    for (int q = 0; q < 2; ++q) {
        float4 v = p[q];
        float vv[4] = {v.x, v.y, v.z, v.w};
        half4v h, l;
        #pragma unroll
        for (int j = 0; j < 4; ++j) {
            _Float16 hj = (_Float16)vv[j];
            h[j] = hj;
            l[j] = (_Float16)(vv[j] - (float)hj);
            s += vv[j] * vv[j];
        }
        size_t di = (size_t)row * D2 + lane * 8 + q * 4;
        *reinterpret_cast<half4v*>(chi + di) = h;
        *reinterpret_cast<half4v*>(clo + di) = l;
    }
    #pragma unroll
    for (int o = 32; o > 0; o >>= 1) s += __shfl_down(s, o, 64);
    if (lane == 0) cnorm[row] = s;
}

// ---------------------------------------------------------------------------
// sig_adj[i] = 0.5*sigmoid(adj[i])  (K*K fp32, LLC-resident afterwards)
__global__ __launch_bounds__(256)
void k_sigadj(const float* __restrict__ adj, float* __restrict__ sig) {
    const int n4 = K * K / 4;
    for (int i = blockIdx.x * blockDim.x + threadIdx.x; i < n4;
         i += gridDim.x * blockDim.x) {
        float4 v = reinterpret_cast<const float4*>(adj)[i];
        float4 o;
        o.x = 0.5f / (1.0f + __expf(-v.x));
        o.y = 0.5f / (1.0f + __expf(-v.y));
        o.z = 0.5f / (1.0f + __expf(-v.z));
        o.w = 0.5f / (1.0f + __expf(-v.w));
        reinterpret_cast<float4*>(sig)[i] = o;
    }
}

// ---------------------------------------------------------------------------
// MFMA score GEMM + fused argmin. Grid: (512 row-panels of 128) x (4 N-slices
// of 512 codewords). K' = 1536 = [hz.hc | hz.lc | lz.hc].
__global__ __launch_bounds__(256)
void k_score(const _Float16* __restrict__ z_hi, const _Float16* __restrict__ z_lo,
             const _Float16* __restrict__ c_hi, const _Float16* __restrict__ c_lo,
             const float* __restrict__ cnorm, const float* __restrict__ sigadj,
             const int* __restrict__ prev,
             float* __restrict__ ws_v, int* __restrict__ ws_i) {
    __shared__ _Float16 As[128 * 32] __attribute__((aligned(16)));  // 8 KB
    __shared__ _Float16 Bs[128 * 32] __attribute__((aligned(16)));  // 8 KB
    __shared__ float s_rv[128][2];
    __shared__ int   s_ri[128][2];

    const int tid  = threadIdx.x;
    const int w    = tid >> 6, lane = tid & 63;
    const int wr   = w >> 1,   wc   = w & 1;      // 2x2 wave grid, 64x64 each
    const int g    = lane >> 4, c   = lane & 15;
    const int row0 = blockIdx.x * 128;
    const int n0   = blockIdx.y * 512;

    // prev[] for the 16 rows this lane's C fragments touch (fixed across nt)
    int pidx[16];
    #pragma unroll
    for (int fm = 0; fm < 4; ++fm)
        #pragma unroll
        for (int j = 0; j < 4; ++j)
            pidx[fm * 4 + j] = prev[row0 + wr * 64 + fm * 16 + g * 4 + j];

    float bestv = 3.0e38f; int besti = 0;   // running argmin, owned by tid<128

    for (int nt = 0; nt < 4; ++nt) {
        floatx4 acc[4][4];
        #pragma unroll
        for (int i = 0; i < 4; ++i)
            #pragma unroll
            for (int j = 0; j < 4; ++j)
                acc[i][j] = (floatx4){0.f, 0.f, 0.f, 0.f};

        for (int ks = 0; ks < 48; ++ks) {
            const int seg = ks >> 4, kk = (ks & 15) * 32;
            const char* asrc = (const char*)((seg < 2 ? z_hi : z_lo)
                                             + (size_t)row0 * D2 + kk);
            const char* bsrc = (const char*)((seg == 1 ? c_lo : c_hi)
                                             + (size_t)(n0 + nt * 128) * D2 + kk);
            __syncthreads();
            #pragma unroll
            for (int r = 0; r < 2; ++r) {
                int slot = r * 4 + w;                 // wave-uniform
                int o    = slot * 1024 + lane * 16;   // byte offset in 8 KB tile
                int trow = o >> 6, tcol = o & 63;     // 64 B per tile-row
                size_t goff = (size_t)trow * 1024 + tcol;  // 1024 B global row
                async16((char*)As + slot * 1024, asrc + goff);
                async16((char*)Bs + slot * 1024, bsrc + goff);
            }
            __syncthreads();

            half8 a[4], b[4];
            const half8* Av = (const half8*)As;
            const half8* Bv = (const half8*)Bs;
            #pragma unroll
            for (int f = 0; f < 4; ++f) {
                a[f] = Av[(wr * 64 + f * 16 + c) * 4 + g];
                b[f] = Bv[(wc * 64 + f * 16 + c) * 4 + g];
            }
            #pragma unroll
            for (int fm = 0; fm < 4; ++fm)
                #pragma unroll
                for (int fn = 0; fn < 4; ++fn)
                    acc[fm][fn] = __builtin_amdgcn_mfma_f32_16x16x32_f16(
                        a[fm], b[fn], acc[fm][fn], 0, 0, 0);
        }

        // ---- fused score + argmin epilogue for this 128-col tile ----
        const int nbase = n0 + nt * 128 + wc * 64;
        float cn[4];
        #pragma unroll
        for (int fn = 0; fn < 4; ++fn) cn[fn] = cnorm[nbase + fn * 16 + c];
        #pragma unroll
        for (int fm = 0; fm < 4; ++fm) {
            #pragma unroll
            for (int j = 0; j < 4; ++j) {
                const float* srow = sigadj + (size_t)pidx[fm * 4 + j] * K;
                float bv = 3.0e38f; int bi = 0;
                #pragma unroll
                for (int fn = 0; fn < 4; ++fn) {
                    int col = nbase + fn * 16 + c;
                    float s = cn[fn] - 2.0f * acc[fm][fn][j] - srow[col];
                    if (s < bv || (s == bv && col < bi)) { bv = s; bi = col; }
                }
                #pragma unroll
                for (int m = 1; m < 16; m <<= 1) {
                    float ov = __shfl_xor(bv, m, 64);
                    int   oi = __shfl_xor(bi, m, 64);
                    if (ov < bv || (ov == bv && oi < bi)) { bv = ov; bi = oi; }
                }
                if (c == 0) {
                    int lr = wr * 64 + fm * 16 + g * 4 + j;
                    s_rv[lr][wc] = bv; s_ri[lr][wc] = bi;
                }
            }
        }
        __syncthreads();
        if (tid < 128) {
            float v0 = s_rv[tid][0], v1 = s_rv[tid][1];
            int   i0 = s_ri[tid][0], i1 = s_ri[tid][1];
            float nv; int ni;
            if (v0 < v1 || (v0 == v1 && i0 < i1)) { nv = v0; ni = i0; }
            else                                  { nv = v1; ni = i1; }
            if (nv < bestv || (nv == bestv && ni < besti)) { bestv = nv; besti = ni; }
        }
        // next nt's staging barrier separates s_rv reuse
    }

    if (tid < 128) {
        int row = row0 + tid;
        ws_v[row * 4 + blockIdx.y] = bestv;
        ws_i[row * 4 + blockIdx.y] = besti;
    }
}

// ---------------------------------------------------------------------------
// Reduce 4 N-slice partials -> final idx; gather z_q; write outputs; loss.
__global__ __launch_bounds__(256)
void k_final(const float* __restrict__ zr, const float* __restrict__ zi,
             const float* __restrict__ cb, const float* __restrict__ ws_v,
             const int* __restrict__ ws_i, float* __restrict__ out_real,
             float* __restrict__ out_imag, float* __restrict__ loss,
             float* __restrict__ out_idx) {
    __shared__ int s_kmin[128];
    const int tid  = threadIdx.x;
    const int row0 = blockIdx.x * 128;

    if (tid < 128) {
        int row = row0 + tid;
        float bv = ws_v[row * 4]; int bi = ws_i[row * 4];
        #pragma unroll
        for (int p = 1; p < 4; ++p) {
            float v = ws_v[row * 4 + p]; int idx = ws_i[row * 4 + p];
            if (v < bv || (v == bv && idx < bi)) { bv = v; bi = idx; }
        }
        s_kmin[tid] = bi;
        out_idx[row] = (float)bi;
    }
    __syncthreads();

    float lsum = 0.0f;
    for (int r = 0; r < 128; ++r) {
        int k  = s_kmin[r];
        int gr = row0 + r;
        float2 c2 = *(const float2*)(cb + (size_t)k * D2 + tid * 2);
        float2 z2; float* outp;
        if (tid < 128) {
            z2   = *(const float2*)(zr + (size_t)gr * D + tid * 2);
            outp = out_real + (size_t)gr * D + tid * 2;
        } else {
            z2   = *(const float2*)(zi + (size_t)gr * D + (tid - 128) * 2);
            outp = out_imag + (size_t)gr * D + (tid - 128) * 2;
        }
        *(float2*)outp = c2;
        float d0 = c2.x - z2.x, d1 = c2.y - z2.y;
        lsum += d0 * d0 + d1 * d1;
    }
    #pragma unroll
    for (int o = 32; o > 0; o >>= 1) lsum += __shfl_down(lsum, o, 64);
    __shared__ float s_ls[4];
    if ((tid & 63) == 0) s_ls[tid >> 6] = lsum;
    __syncthreads();
    if (tid == 0)
        atomicAdd(loss, (s_ls[0] + s_ls[1] + s_ls[2] + s_ls[3]) * LOSS_SCALE);
}

// ---------------------------------------------------------------------------
extern "C" void kernel_launch(void* const* d_in, const int* in_sizes, int n_in,
                              void* d_out, int out_size, void* d_ws, size_t ws_size,
                              hipStream_t stream) {
    const float* zr   = (const float*)d_in[0];
    const float* zi   = (const float*)d_in[1];
    const int*   prev = (const int*)  d_in[2];
    const float* cb   = (const float*)d_in[3];
    const float* adj  = (const float*)d_in[4];

    float* out      = (float*)d_out;
    float* out_real = out;
    float* out_imag = out + (size_t)R_TOT * D;
    float* loss     = out + (size_t)2 * R_TOT * D;
    float* out_idx  = loss + 1;

    char* w = (char*)d_ws;
    _Float16* z_hi  = (_Float16*)w;  w += (size_t)R_TOT * D2 * 2;  // 67 MB
    _Float16* z_lo  = (_Float16*)w;  w += (size_t)R_TOT * D2 * 2;  // 67 MB
    _Float16* c_hi  = (_Float16*)w;  w += (size_t)K * D2 * 2;      // 2 MB
    _Float16* c_lo  = (_Float16*)w;  w += (size_t)K * D2 * 2;      // 2 MB
    float*    cnorm = (float*)w;     w += (size_t)K * 4;
    float*    sigadj= (float*)w;     w += (size_t)K * K * 4;       // 16.8 MB
    float*    ws_v  = (float*)w;     w += (size_t)R_TOT * 4 * 4;   // 1 MB
    int*      ws_i  = (int*)w;       w += (size_t)R_TOT * 4 * 4;   // 1 MB

    hipMemsetAsync(loss, 0, sizeof(float), stream);
    k_split   <<<2048, 256, 0, stream>>>(zr, z_hi, z_lo, 0);
    k_split   <<<2048, 256, 0, stream>>>(zi, z_hi, z_lo, 256);
    k_split_cb<<<K / 4, 256, 0, stream>>>(cb, c_hi, c_lo, cnorm);
    k_sigadj  <<<2048, 256, 0, stream>>>(adj, sigadj);
    k_score   <<<dim3(R_TOT / 128, 4), 256, 0, stream>>>(
        z_hi, z_lo, c_hi, c_lo, cnorm, sigadj, prev, ws_v, ws_i);
    k_final   <<<R_TOT / 128, 256, 0, stream>>>(
        zr, zi, cb, ws_v, ws_i, out_real, out_imag, loss, out_idx);
}

// Round 3
// 1048.683 us; speedup vs baseline: 2.2456x; 1.2038x over previous
//
#include <hip/hip_runtime.h>
#include <math.h>

typedef _Float16 half8 __attribute__((ext_vector_type(8)));
typedef _Float16 half4v __attribute__((ext_vector_type(4)));
typedef float floatx4 __attribute__((ext_vector_type(4)));

constexpr int R_TOT = 65536;   // B*S
constexpr int D     = 256;
constexpr int D2    = 512;
constexpr int K     = 2048;
constexpr float LOSS_SCALE = 1.25f / ((float)R_TOT * (float)D2);

// async global->LDS, 16B per lane; LDS dest = wave-uniform base + lane*16
__device__ __forceinline__ void async16(void* lds, const void* g) {
    __builtin_amdgcn_global_load_lds(
        (const __attribute__((address_space(1))) unsigned int*)g,
        (__attribute__((address_space(3))) unsigned int*)lds,
        16, 0, 0);
}

// ---------------------------------------------------------------------------
// Split one fp32 [R][256] source into hi/lo fp16 halves of [R][512] dest.
__global__ __launch_bounds__(256)
void k_split(const float* __restrict__ src, _Float16* __restrict__ dhi,
             _Float16* __restrict__ dlo, int coloff) {
    const int n4 = R_TOT * 64;                       // float4 count
    for (int i = blockIdx.x * blockDim.x + threadIdx.x; i < n4;
         i += gridDim.x * blockDim.x) {
        int row = i >> 6, c4 = i & 63;
        float4 v = reinterpret_cast<const float4*>(src)[i];
        float vv[4] = {v.x, v.y, v.z, v.w};
        half4v h, l;
        #pragma unroll
        for (int j = 0; j < 4; ++j) {
            _Float16 hj = (_Float16)vv[j];
            h[j] = hj;
            l[j] = (_Float16)(vv[j] - (float)hj);
        }
        size_t di = (size_t)row * D2 + coloff + c4 * 4;
        *reinterpret_cast<half4v*>(dhi + di) = h;
        *reinterpret_cast<half4v*>(dlo + di) = l;
    }
}

// ---------------------------------------------------------------------------
// Split codebook [K][512] into hi/lo fp16 + exact fp32 row norms. Wave/row.
__global__ __launch_bounds__(256)
void k_split_cb(const float* __restrict__ cb, _Float16* __restrict__ chi,
                _Float16* __restrict__ clo, float* __restrict__ cnorm) {
    int row  = blockIdx.x * 4 + (threadIdx.x >> 6);
    int lane = threadIdx.x & 63;
    const float4* p = reinterpret_cast<const float4*>(cb + (size_t)row * D2 + lane * 8);
    float s = 0.0f;
    #pragma unroll
    for (int q = 0; q < 2; ++q) {
        float4 v = p[q];
        float vv[4] = {v.x, v.y, v.z, v.w};
        half4v h, l;
        #pragma unroll
        for (int j = 0; j < 4; ++j) {
            _Float16 hj = (_Float16)vv[j];
            h[j] = hj;
            l[j] = (_Float16)(vv[j] - (float)hj);
            s += vv[j] * vv[j];
        }
        size_t di = (size_t)row * D2 + lane * 8 + q * 4;
        *reinterpret_cast<half4v*>(chi + di) = h;
        *reinterpret_cast<half4v*>(clo + di) = l;
    }
    #pragma unroll
    for (int o = 32; o > 0; o >>= 1) s += __shfl_down(s, o, 64);
    if (lane == 0) cnorm[row] = s;
}

// ---------------------------------------------------------------------------
// sig_adj[i] = 0.5*sigmoid(adj[i])  (K*K fp32, L2/LLC-resident afterwards)
__global__ __launch_bounds__(256)
void k_sigadj(const float* __restrict__ adj, float* __restrict__ sig) {
    const int n4 = K * K / 4;
    for (int i = blockIdx.x * blockDim.x + threadIdx.x; i < n4;
         i += gridDim.x * blockDim.x) {
        float4 v = reinterpret_cast<const float4*>(adj)[i];
        float4 o;
        o.x = 0.5f / (1.0f + __expf(-v.x));
        o.y = 0.5f / (1.0f + __expf(-v.y));
        o.z = 0.5f / (1.0f + __expf(-v.z));
        o.w = 0.5f / (1.0f + __expf(-v.w));
        reinterpret_cast<float4*>(sig)[i] = o;
    }
}

// ---------------------------------------------------------------------------
// MFMA score GEMM + fused per-lane argmin. One 128x128 output tile per block,
// continuous K' = 1536 = [hz.hc | hz.lc | lz.hc]. Partials out via packed
// (score,idx) atomicMin (order-independent, ties -> smaller idx).
// Grid: dim3(16 slices, 512 panels) so consecutive blocks share the A panel.
__global__ __launch_bounds__(256)
void k_score(const _Float16* __restrict__ z_hi, const _Float16* __restrict__ z_lo,
             const _Float16* __restrict__ c_hi, const _Float16* __restrict__ c_lo,
             const float* __restrict__ cnorm, const float* __restrict__ sigadj,
             const int* __restrict__ prev,
             unsigned long long* __restrict__ ws_key) {
    __shared__ _Float16 As[128 * 32] __attribute__((aligned(16)));  // 8 KB
    __shared__ _Float16 Bs[128 * 32] __attribute__((aligned(16)));  // 8 KB

    const int tid  = threadIdx.x;
    const int w    = tid >> 6, lane = tid & 63;
    const int wr   = w >> 1,   wc   = w & 1;      // 2x2 wave grid, 64x64 each
    const int g    = lane >> 4, c   = lane & 15;
    const int n0   = blockIdx.x * 128;
    const int row0 = blockIdx.y * 128;

    floatx4 acc[4][4];
    #pragma unroll
    for (int i = 0; i < 4; ++i)
        #pragma unroll
        for (int j = 0; j < 4; ++j)
            acc[i][j] = (floatx4){0.f, 0.f, 0.f, 0.f};

    for (int ks = 0; ks < 48; ++ks) {
        const int seg = ks >> 4, kk = (ks & 15) * 32;
        const char* asrc = (const char*)((seg < 2 ? z_hi : z_lo)
                                         + (size_t)row0 * D2 + kk);
        const char* bsrc = (const char*)((seg == 1 ? c_lo : c_hi)
                                         + (size_t)n0 * D2 + kk);
        __syncthreads();
        #pragma unroll
        for (int r = 0; r < 2; ++r) {
            int slot = r * 4 + w;                 // wave-uniform
            int o    = slot * 1024 + lane * 16;   // byte offset in 8 KB tile
            int trow = o >> 6, tcol = o & 63;     // 64 B per tile-row
            size_t goff = (size_t)trow * 1024 + tcol;  // 1024 B global row
            async16((char*)As + slot * 1024, asrc + goff);
            async16((char*)Bs + slot * 1024, bsrc + goff);
        }
        __syncthreads();

        half8 a[4], b[4];
        const half8* Av = (const half8*)As;
        const half8* Bv = (const half8*)Bs;
        #pragma unroll
        for (int f = 0; f < 4; ++f) {
            a[f] = Av[(wr * 64 + f * 16 + c) * 4 + g];
            b[f] = Bv[(wc * 64 + f * 16 + c) * 4 + g];
        }
        #pragma unroll
        for (int fm = 0; fm < 4; ++fm)
            #pragma unroll
            for (int fn = 0; fn < 4; ++fn)
                acc[fm][fn] = __builtin_amdgcn_mfma_f32_16x16x32_f16(
                    a[fm], b[fn], acc[fm][fn], 0, 0, 0);
    }

    // ---- fused score + argmin epilogue (once per block) ----
    const int nbase = n0 + wc * 64;
    float cn[4];
    #pragma unroll
    for (int fn = 0; fn < 4; ++fn) cn[fn] = cnorm[nbase + fn * 16 + c];

    #pragma unroll
    for (int fm = 0; fm < 4; ++fm) {
        #pragma unroll
        for (int j = 0; j < 4; ++j) {
            const int row = row0 + wr * 64 + fm * 16 + g * 4 + j;
            const float* srow = sigadj + (size_t)prev[row] * K;
            float bv = 3.0e38f; int bi = 0;
            #pragma unroll
            for (int fn = 0; fn < 4; ++fn) {
                int col = nbase + fn * 16 + c;
                float s = cn[fn] - 2.0f * acc[fm][fn][j] - srow[col];
                if (s < bv || (s == bv && col < bi)) { bv = s; bi = col; }
            }
            #pragma unroll
            for (int m = 1; m < 16; m <<= 1) {
                float ov = __shfl_xor(bv, m, 64);
                int   oi = __shfl_xor(bi, m, 64);
                if (ov < bv || (ov == bv && oi < bi)) { bv = ov; bi = oi; }
            }
            if (c == 0) {
                unsigned u = __float_as_uint(bv);
                u = (u & 0x80000000u) ? ~u : (u | 0x80000000u);
                unsigned long long key = ((unsigned long long)u << 32) | (unsigned)bi;
                atomicMin(&ws_key[row], key);
            }
        }
    }
}

// ---------------------------------------------------------------------------
// Decode keys -> final idx; gather z_q; write outputs; loss (float4 path).
__global__ __launch_bounds__(256)
void k_final(const float* __restrict__ zr, const float* __restrict__ zi,
             const float* __restrict__ cb,
             const unsigned long long* __restrict__ ws_key,
             float* __restrict__ out_real, float* __restrict__ out_imag,
             float* __restrict__ loss, float* __restrict__ out_idx) {
    __shared__ int s_kmin[128];
    const int tid  = threadIdx.x;
    const int row0 = blockIdx.x * 128;

    if (tid < 128) {
        unsigned long long key = ws_key[row0 + tid];
        int bi = (int)(unsigned)(key & 0xFFFFFFFFu);
        s_kmin[tid] = bi;
        out_idx[row0 + tid] = (float)bi;
    }
    __syncthreads();

    float lsum = 0.0f;
    for (int it = 0; it < 64; ++it) {
        int r  = it * 2 + (tid >> 7);
        int k  = s_kmin[r];
        int gr = row0 + r;
        int q  = tid & 127;
        float4 c4 = *(const float4*)(cb + (size_t)k * D2 + q * 4);
        float4 z4; float* outp;
        if (q < 64) {
            z4   = *(const float4*)(zr + (size_t)gr * D + q * 4);
            outp = out_real + (size_t)gr * D + q * 4;
        } else {
            z4   = *(const float4*)(zi + (size_t)gr * D + (q - 64) * 4);
            outp = out_imag + (size_t)gr * D + (q - 64) * 4;
        }
        *(float4*)outp = c4;
        float dx = c4.x - z4.x, dy = c4.y - z4.y;
        float dz = c4.z - z4.z, dw = c4.w - z4.w;
        lsum += dx * dx + dy * dy + dz * dz + dw * dw;
    }
    #pragma unroll
    for (int o = 32; o > 0; o >>= 1) lsum += __shfl_down(lsum, o, 64);
    __shared__ float s_ls[4];
    if ((tid & 63) == 0) s_ls[tid >> 6] = lsum;
    __syncthreads();
    if (tid == 0)
        atomicAdd(loss, (s_ls[0] + s_ls[1] + s_ls[2] + s_ls[3]) * LOSS_SCALE);
}

// ---------------------------------------------------------------------------
extern "C" void kernel_launch(void* const* d_in, const int* in_sizes, int n_in,
                              void* d_out, int out_size, void* d_ws, size_t ws_size,
                              hipStream_t stream) {
    const float* zr   = (const float*)d_in[0];
    const float* zi   = (const float*)d_in[1];
    const int*   prev = (const int*)  d_in[2];
    const float* cb   = (const float*)d_in[3];
    const float* adj  = (const float*)d_in[4];

    float* out      = (float*)d_out;
    float* out_real = out;
    float* out_imag = out + (size_t)R_TOT * D;
    float* loss     = out + (size_t)2 * R_TOT * D;
    float* out_idx  = loss + 1;

    char* w = (char*)d_ws;
    _Float16* z_hi  = (_Float16*)w;  w += (size_t)R_TOT * D2 * 2;  // 67 MB
    _Float16* z_lo  = (_Float16*)w;  w += (size_t)R_TOT * D2 * 2;  // 67 MB
    _Float16* c_hi  = (_Float16*)w;  w += (size_t)K * D2 * 2;      // 2 MB
    _Float16* c_lo  = (_Float16*)w;  w += (size_t)K * D2 * 2;      // 2 MB
    float*    cnorm = (float*)w;     w += (size_t)K * 4;
    float*    sigadj= (float*)w;     w += (size_t)K * K * 4;       // 16.8 MB
    unsigned long long* ws_key = (unsigned long long*)w; w += (size_t)R_TOT * 8;

    hipMemsetAsync(loss, 0, sizeof(float), stream);
    hipMemsetAsync(ws_key, 0xFF, (size_t)R_TOT * 8, stream);
    k_split   <<<2048, 256, 0, stream>>>(zr, z_hi, z_lo, 0);
    k_split   <<<2048, 256, 0, stream>>>(zi, z_hi, z_lo, 256);
    k_split_cb<<<K / 4, 256, 0, stream>>>(cb, c_hi, c_lo, cnorm);
    k_sigadj  <<<2048, 256, 0, stream>>>(adj, sigadj);
    k_score   <<<dim3(16, 512), 256, 0, stream>>>(
        z_hi, z_lo, c_hi, c_lo, cnorm, sigadj, prev, ws_key);
    k_final   <<<R_TOT / 128, 256, 0, stream>>>(
        zr, zi, cb, ws_key, out_real, out_imag, loss, out_idx);
}